// Round 3
// baseline (1323.255 us; speedup 1.0000x reference)
//
#include <hip/hip_runtime.h>

#define NB 8
#define CIN 512
#define CO 128
#define NS 16
#define NHW 4096
#define NR 3
#define NK 64
#define KMITERS 10

typedef __attribute__((ext_vector_type(8))) short s16x8;
typedef __attribute__((ext_vector_type(4))) float f32x4;

// Truncating hi/lo bf16 split: x ~= hi + lo with |err| <= 2^-16 |x|.
static __device__ __forceinline__ void bsplit(float x, short& h, short& l) {
    union { float f; unsigned u; } a; a.f = x;
    h = (short)(a.u >> 16);
    union { unsigned u; float f; } hf; hf.u = a.u & 0xFFFF0000u;
    union { float f; unsigned u; } r; r.f = x - hf.f;
    l = (short)(r.u >> 16);
}

// ---------------------------------------------------------------------------
// MFMA bf16x3 1x1-conv GEMM (ref branch ONLY — smooth consumers, loose tol):
// out[g,m,n] = sum_c W[m,c]*X[g,c,n] + bias[m]
// ---------------------------------------------------------------------------
__global__ __launch_bounds__(256) void conv_mfma(const float* __restrict__ X,
    const float* __restrict__ Wt, const float* __restrict__ bias, float* __restrict__ out)
{
    __shared__ short sWh[128 * 40];  // [m][k] pad 40 (16B-aligned frag reads)
    __shared__ short sWl[128 * 40];
    __shared__ float sX[32 * 133];   // [k][n] pad 133 (conflict-free column reads)
    const int g = blockIdx.y;
    const int n0 = blockIdx.x * 128;
    const int tid = threadIdx.x;
    const int lane = tid & 63, w = tid >> 6;
    const int l15 = lane & 15, quad = lane >> 4;
    const int wm = (w & 1) * 64, wn = (w >> 1) * 64;

    f32x4 acc[4][4];
#pragma unroll
    for (int i = 0; i < 4; ++i)
#pragma unroll
        for (int j = 0; j < 4; ++j) acc[i][j] = (f32x4){0.f, 0.f, 0.f, 0.f};

    for (int c0 = 0; c0 < CIN; c0 += 32) {
        if (c0) __syncthreads();
#pragma unroll
        for (int r = 0; r < 4; ++r) {
            int e = r * 1024 + tid * 4;
            int m = e >> 5, cc = e & 31;
            const float4 wv = *(const float4*)&Wt[(size_t)m * CIN + c0 + cc];
            short h0, l0, h1, l1, h2, l2, h3, l3;
            bsplit(wv.x, h0, l0); bsplit(wv.y, h1, l1);
            bsplit(wv.z, h2, l2); bsplit(wv.w, h3, l3);
            *(short4*)&sWh[m * 40 + cc] = make_short4(h0, h1, h2, h3);
            *(short4*)&sWl[m * 40 + cc] = make_short4(l0, l1, l2, l3);
        }
#pragma unroll
        for (int r = 0; r < 4; ++r) {
            int e = r * 1024 + tid * 4;
            int k = e >> 7, n = e & 127;
            const float4 xv = *(const float4*)&X[((size_t)g * CIN + c0 + k) * NHW + n0 + n];
            float* p = &sX[k * 133 + n];
            p[0] = xv.x; p[1] = xv.y; p[2] = xv.z; p[3] = xv.w;
        }
        __syncthreads();

        s16x8 ah[4], al[4];
#pragma unroll
        for (int mt = 0; mt < 4; ++mt) {
            int m = wm + mt * 16 + l15;
            ah[mt] = *(const s16x8*)&sWh[m * 40 + quad * 8];
            al[mt] = *(const s16x8*)&sWl[m * 40 + quad * 8];
        }
#pragma unroll
        for (int nt = 0; nt < 4; ++nt) {
            int n = wn + nt * 16 + l15;
            s16x8 bh, bl;
#pragma unroll
            for (int jj = 0; jj < 8; ++jj) {
                float xv = sX[(quad * 8 + jj) * 133 + n];
                short h, l; bsplit(xv, h, l);
                bh[jj] = h; bl[jj] = l;
            }
#pragma unroll
            for (int mt = 0; mt < 4; ++mt) {
                acc[mt][nt] = __builtin_amdgcn_mfma_f32_16x16x32_bf16(ah[mt], bh, acc[mt][nt], 0, 0, 0);
                acc[mt][nt] = __builtin_amdgcn_mfma_f32_16x16x32_bf16(ah[mt], bl, acc[mt][nt], 0, 0, 0);
                acc[mt][nt] = __builtin_amdgcn_mfma_f32_16x16x32_bf16(al[mt], bh, acc[mt][nt], 0, 0, 0);
            }
        }
    }
    // C/D layout: col = lane&15, row = quad*4 + reg
#pragma unroll
    for (int mt = 0; mt < 4; ++mt) {
#pragma unroll
        for (int reg = 0; reg < 4; ++reg) {
            int m = wm + mt * 16 + quad * 4 + reg;
            float bv = bias[m];
#pragma unroll
            for (int nt = 0; nt < 4; ++nt) {
                int n = wn + nt * 16 + l15;
                out[((size_t)g * CO + m) * NHW + n0 + n] = acc[mt][nt][reg] + bv;
            }
        }
    }
}

// ---------------------------------------------------------------------------
// Exact fp32 VALU conv — target branch. KMEANS-EXACTNESS INVARIANT: each
// output element is ONE sequential fmaf chain over c = 0..CIN-1 ascending.
// This retiling (float4 staging + float4 LDS reads + TM4xTN8) preserves that
// chain exactly -> out0 is BIT-IDENTICAL to the R2-verified zero-flip config.
// Column groups per thread: [tn*4..+3] and [BN/2 + tn*4..+3] so each b128
// read hits slot-consecutive LDS (no 4-way 16B-slot aliasing).
// ---------------------------------------------------------------------------
template<int BM, int BN, int BK, int TM, int TN>
__global__ __launch_bounds__(256) void conv1x1(const float* __restrict__ X,
    const float* __restrict__ Wt, const float* __restrict__ bias,
    float* __restrict__ outf)
{
    static_assert(TM == 4 && (TN == 4 || TN == 8), "mapping assumes TM=4");
    __shared__ float sW[BK][BM + 4];   // +4 keeps 16B row alignment
    __shared__ float sX2[BK][BN + 4];
    const int g  = blockIdx.z;
    const int m0 = blockIdx.y * BM;
    const int n0 = blockIdx.x * BN;
    const int tid = threadIdx.x;
    constexpr int NTH_N = BN / TN;
    const int tn = tid % NTH_N;
    const int tm = tid / NTH_N;
    const int O = gridDim.y * BM;
    const int cb0 = tn * 4;
    const int cb1 = BN / 2 + tn * 4;   // TN==8 only

    float acc[TM][TN];
#pragma unroll
    for (int i = 0; i < TM; ++i)
#pragma unroll
        for (int j = 0; j < TN; ++j) acc[i][j] = 0.f;

    for (int c0 = 0; c0 < CIN; c0 += BK) {
        if (c0) __syncthreads();
        constexpr int F4R = BK / 4;
        for (int idx4 = tid; idx4 < BM * F4R; idx4 += 256) {
            int m = idx4 / F4R, cw = (idx4 % F4R) * 4;
            const float4 wv = *(const float4*)&Wt[(size_t)(m0 + m) * CIN + c0 + cw];
            sW[cw][m] = wv.x; sW[cw + 1][m] = wv.y;
            sW[cw + 2][m] = wv.z; sW[cw + 3][m] = wv.w;
        }
        constexpr int F4N = BN / 4;
        for (int idx4 = tid; idx4 < BK * F4N; idx4 += 256) {
            int k = idx4 / F4N, n4 = (idx4 % F4N) * 4;
            *(float4*)&sX2[k][n4] =
                *(const float4*)&X[((size_t)g * CIN + c0 + k) * NHW + n0 + n4];
        }
        __syncthreads();
#pragma unroll
        for (int k = 0; k < BK; ++k) {
            float a[TM], bb[TN];
            *(float4*)&a[0] = *(const float4*)&sW[k][tm * 4];
            *(float4*)&bb[0] = *(const float4*)&sX2[k][cb0];
            if constexpr (TN == 8)
                *(float4*)&bb[4] = *(const float4*)&sX2[k][cb1];
#pragma unroll
            for (int i = 0; i < TM; ++i)
#pragma unroll
                for (int j = 0; j < TN; ++j) acc[i][j] = fmaf(a[i], bb[j], acc[i][j]);
        }
    }
#pragma unroll
    for (int i = 0; i < TM; ++i) {
        int m = m0 + tm * 4 + i;
        float bv = bias[m];
        float4 o0;
        o0.x = acc[i][0] + bv; o0.y = acc[i][1] + bv;
        o0.z = acc[i][2] + bv; o0.w = acc[i][3] + bv;
        *(float4*)&outf[((size_t)g * O + m) * NHW + n0 + cb0] = o0;
        if constexpr (TN == 8) {
            float4 o1;
            o1.x = acc[i][4] + bv; o1.y = acc[i][5] + bv;
            o1.z = acc[i][6] + bv; o1.w = acc[i][7] + bv;
            *(float4*)&outf[((size_t)g * O + m) * NHW + n0 + cb1] = o1;
        }
    }
}

// ---------------------------------------------------------------------------
// KMeans
// ---------------------------------------------------------------------------
__global__ void km_init(const float* __restrict__ xt, float* __restrict__ cent) {
    int idx = blockIdx.x * 256 + threadIdx.x;
    if (idx >= NB * NK * CO) return;
    int c = idx % CO;
    int k = (idx / CO) % NK;
    int b = idx / (CO * NK);
    cent[idx] = xt[((size_t)b * CO + c) * NHW + 65 * k];
}

// grid (32, NB), 1024 thr, 128 points/block. Per-point distance math is the
// EXACT same ascending-c fmaf chain + argmin/tie order as the verified 256-thr
// version (1 pt/thread instead of 4) -> labels bit-identical given same
// centroids. Full X slab staged once in LDS (102 KB, 1 block/CU by grid).
// Phase-2 atomic accumulation keeps the original 256-thread mapping.
__global__ __launch_bounds__(1024) void km_label(const float* __restrict__ xt,
    const float* __restrict__ cent, float* __restrict__ psums, float* __restrict__ pcnt)
{
    __shared__ float sCent[64 * 129];  // phase1: centroids; phase2: cluster sums
    __shared__ float sXs[128 * 133];   // full [c][n] slab for this block
    __shared__ float sC2[64];
    __shared__ float sCnt[64];
    __shared__ int sLab[128];
    const int b = blockIdx.y, nb = blockIdx.x;
    const int n0 = nb * 128;
    const int tid = threadIdx.x;

#pragma unroll
    for (int r = 0; r < 2; ++r) {
        int e = r * 4096 + tid * 4;
        int k = e >> 7, c = e & 127;
        const float4 cv = *(const float4*)&cent[((size_t)b * NK + k) * CO + c];
        float* p = &sCent[k * 129 + c];
        p[0] = cv.x; p[1] = cv.y; p[2] = cv.z; p[3] = cv.w;
    }
#pragma unroll
    for (int r = 0; r < 4; ++r) {
        int e = r * 4096 + tid * 4;
        int c = e >> 7, n = e & 127;
        const float4 xv = *(const float4*)&xt[((size_t)b * CO + c) * NHW + n0 + n];
        float* p = &sXs[c * 133 + n];
        p[0] = xv.x; p[1] = xv.y; p[2] = xv.z; p[3] = xv.w;
    }
    __syncthreads();
    if (tid < 64) {
        float s = 0.f;
        for (int c = 0; c < CO; ++c) { float v = sCent[tid * 129 + c]; s = fmaf(v, v, s); }
        sC2[tid] = s;
    }
    __syncthreads();

    const int tn = tid & 7, tm = tid >> 3;   // 1 pt x 8 clusters per thread
    float dot[8];
    float p2 = 0.f;
#pragma unroll
    for (int j = 0; j < 8; ++j) dot[j] = 0.f;
    for (int cc = 0; cc < 4; ++cc) {
        for (int c4 = 0; c4 < 8; ++c4) {
            float xv[4];
#pragma unroll
            for (int j = 0; j < 4; ++j)
                xv[j] = sXs[(cc * 32 + c4 * 4 + j) * 133 + tm];
#pragma unroll
            for (int j = 0; j < 4; ++j)
                p2 = fmaf(xv[j], xv[j], p2);
#pragma unroll
            for (int jj = 0; jj < 8; ++jj) {
                int k = tn * 8 + jj;
#pragma unroll
                for (int j = 0; j < 4; ++j) {
                    float cv = sCent[k * 129 + cc * 32 + c4 * 4 + j];
                    dot[jj] = fmaf(xv[j], cv, dot[jj]);
                }
            }
        }
    }
    // argmin, first-min tie semantics (within thread ascending k, then lanes)
    {
        int lab = tn * 8;
        float bd = p2 + sC2[tn * 8] - 2.f * dot[0];
#pragma unroll
        for (int jj = 1; jj < 8; ++jj) {
            int k = tn * 8 + jj;
            float d = p2 + sC2[k] - 2.f * dot[jj];
            if (d < bd) { bd = d; lab = k; }
        }
#pragma unroll
        for (int off = 1; off < 8; off <<= 1) {
            float d2 = __shfl_xor(bd, off);
            int l2 = __shfl_xor(lab, off);
            if (d2 < bd || (d2 == bd && l2 < lab)) { bd = d2; lab = l2; }
        }
        if (tn == 0) sLab[tm] = lab;
    }
    __syncthreads();
    for (int e = tid; e < 64 * 129; e += 1024) sCent[e] = 0.f;
    if (tid < 64) sCnt[tid] = 0.f;
    __syncthreads();
    if (tid < 128) atomicAdd(&sCnt[sLab[tid]], 1.f);
    if (tid < 256) {
        const int cq = tid & 31, sh = tid >> 5;
        for (int cc = 0; cc < 4; ++cc) {
            int c = cc * 32 + cq;
            for (int ii = 0; ii < 16; ++ii) {
                int p = sh * 16 + ii;
                atomicAdd(&sCent[sLab[p] * 129 + c], sXs[c * 133 + p]);
            }
        }
    }
    __syncthreads();
    float* ps = &psums[((size_t)b * 32 + nb) * (NK * CO)];
    for (int e = tid; e < NK * CO; e += 1024) {
        int k = e >> 7, c = e & 127;
        ps[e] = sCent[k * 129 + c];
    }
    if (tid < 64) pcnt[((size_t)b * 32 + nb) * 64 + tid] = sCnt[tid];
}

// grid (NK, NB), 128 thr: reduce 32 partials; mode 0 -> centroid update, 1 -> tpt
__global__ void km_update2(float* __restrict__ cent, float* __restrict__ tpt,
    const float* __restrict__ psums, const float* __restrict__ pcnt, int mode)
{
    const int k = blockIdx.x, b = blockIdx.y, c = threadIdx.x;
    float s = 0.f;
    for (int nb = 0; nb < 32; ++nb)
        s += psums[((size_t)b * 32 + nb) * (NK * CO) + k * CO + c];
    if (mode) { tpt[((size_t)b * NK + k) * CO + c] = s; return; }
    float cn = 0.f;
    for (int nb = 0; nb < 32; ++nb)
        cn += pcnt[((size_t)b * 32 + nb) * 64 + k];
    if (cn > 0.f) cent[((size_t)b * NK + k) * CO + c] = s / fmaxf(cn, 1.f);
}

// ---------------------------------------------------------------------------
// Slot branch
// ---------------------------------------------------------------------------
__global__ void slot_softmax(const float* __restrict__ ssb, float* __restrict__ out4) {
    int idx = blockIdx.x * 256 + threadIdx.x;
    if (idx >= NB * NHW) return;
    int b = idx / NHW, n = idx % NHW;
    float v[NS];
    float m = -1e30f;
#pragma unroll
    for (int s = 0; s < NS; ++s) { v[s] = ssb[((size_t)b * NS + s) * NHW + n]; m = fmaxf(m, v[s]); }
    float sum = 0.f;
#pragma unroll
    for (int s = 0; s < NS; ++s) { v[s] = expf(v[s] - m); sum += v[s]; }
    float inv = 1.f / sum;
#pragma unroll
    for (int s = 0; s < NS; ++s)
        out4[((size_t)b * NS + s) * NHW + n] = v[s] * inv;
}

__global__ __launch_bounds__(256) void slot_pt_kernel(const float* __restrict__ ss,
    const float* __restrict__ xt, float* __restrict__ spt)
{
    __shared__ float sS[NS][257];
    __shared__ float sX2[32][257];
    const int b = blockIdx.y;
    const int n0 = blockIdx.x * 256;
    const int tid = threadIdx.x;
    for (int i = tid; i < NS * 256; i += 256) {
        int s = i >> 8, nn = i & 255;
        sS[s][nn] = ss[((size_t)b * NS + s) * NHW + n0 + nn];
    }
    const int c = tid & 31;
    const int sA = tid >> 5;
    for (int cg = 0; cg < 4; ++cg) {
        __syncthreads();
        for (int i = tid; i < 32 * 256; i += 256) {
            int cc = i >> 8, nn = i & 255;
            sX2[cc][nn] = xt[((size_t)b * CO + cg * 32 + cc) * NHW + n0 + nn];
        }
        __syncthreads();
        float a0 = 0.f, a1 = 0.f;
        for (int nn = 0; nn < 256; ++nn) {
            float x = sX2[c][nn];
            a0 = fmaf(x, sS[sA][nn], a0);
            a1 = fmaf(x, sS[sA + 8][nn], a1);
        }
        atomicAdd(&spt[((size_t)b * NS + sA) * CO + cg * 32 + c], a0);
        atomicAdd(&spt[((size_t)b * NS + sA + 8) * CO + cg * 32 + c], a1);
    }
}

// ---------------------------------------------------------------------------
// Ref branch
// ---------------------------------------------------------------------------
__global__ __launch_bounds__(256) void rowstats(const float* __restrict__ xr,
    float* __restrict__ rmax, float* __restrict__ rinv)
{
    const int row = blockIdx.x;
    const float* p = xr + (size_t)row * NHW;
    const int tid = threadIdx.x;
    float v[16];
    float m = -1e30f;
#pragma unroll
    for (int i = 0; i < 16; ++i) { v[i] = p[tid + (i << 8)]; m = fmaxf(m, v[i]); }
#pragma unroll
    for (int off = 32; off; off >>= 1) m = fmaxf(m, __shfl_down(m, off));
    __shared__ float sm[4];
    __shared__ float ss2[4];
    const int wid = tid >> 6, lane = tid & 63;
    if (lane == 0) sm[wid] = m;
    __syncthreads();
    m = fmaxf(fmaxf(sm[0], sm[1]), fmaxf(sm[2], sm[3]));
    float s = 0.f;
#pragma unroll
    for (int i = 0; i < 16; ++i) s += expf(v[i] - m);
#pragma unroll
    for (int off = 32; off; off >>= 1) s += __shfl_down(s, off);
    if (lane == 0) ss2[wid] = s;
    __syncthreads();
    if (tid == 0) {
        rmax[row] = m;
        rinv[row] = 1.f / (ss2[0] + ss2[1] + ss2[2] + ss2[3]);
    }
}

// ref_pt[g,c,d] = sum_n softmax(xr[g,c,:])[n] * xr[g,d,n]
// MFMA bf16x3, spatial-split, fp32 atomicAdd into zeroed out2.
__global__ __launch_bounds__(256) void refpt_mfma(const float* __restrict__ xr,
    const float* __restrict__ rmax, const float* __restrict__ rinv,
    float* __restrict__ refpt)
{
    __shared__ short sSh[128 * 40];  // softmax(S) hi   [c][k] pad 40
    __shared__ short sSl[128 * 40];  // softmax(S) lo
    __shared__ short sXh[128 * 40];  // raw X hi        [d][k] pad 40
    __shared__ short sXl[128 * 40];  // raw X lo
    __shared__ float sMax[CO];
    __shared__ float sInv[CO];
    const int g = blockIdx.y;
    const int n0 = blockIdx.x * 256;   // this block's 256-wide spatial chunk
    const int tid = threadIdx.x;
    const int lane = tid & 63, w = tid >> 6;
    const int l15 = lane & 15, quad = lane >> 4;
    const int wm = (w & 1) * 64, wn = (w >> 1) * 64;
    const float* base = xr + (size_t)g * CO * NHW;

    if (tid < CO) {
        sMax[tid] = rmax[g * CO + tid];
        sInv[tid] = rinv[g * CO + tid];
    }

    f32x4 acc[4][4];
#pragma unroll
    for (int i = 0; i < 4; ++i)
#pragma unroll
        for (int j = 0; j < 4; ++j) acc[i][j] = (f32x4){0.f, 0.f, 0.f, 0.f};

    for (int ks = 0; ks < 8; ++ks) {   // 8 sub-chunks of 32 spatial cols
        __syncthreads();               // covers sMax init and prev-iter reads
#pragma unroll
        for (int r = 0; r < 4; ++r) {
            int e = r * 1024 + tid * 4;
            int row = e >> 5, col = e & 31;
            const float4 xv = *(const float4*)&base[(size_t)row * NHW + n0 + ks * 32 + col];
            const float mx = sMax[row], iv = sInv[row];
            short h0, l0, h1, l1, h2, l2, h3, l3;
            bsplit(xv.x, h0, l0); bsplit(xv.y, h1, l1);
            bsplit(xv.z, h2, l2); bsplit(xv.w, h3, l3);
            *(short4*)&sXh[row * 40 + col] = make_short4(h0, h1, h2, h3);
            *(short4*)&sXl[row * 40 + col] = make_short4(l0, l1, l2, l3);
            float s0 = expf(xv.x - mx) * iv, s1 = expf(xv.y - mx) * iv;
            float s2 = expf(xv.z - mx) * iv, s3 = expf(xv.w - mx) * iv;
            bsplit(s0, h0, l0); bsplit(s1, h1, l1);
            bsplit(s2, h2, l2); bsplit(s3, h3, l3);
            *(short4*)&sSh[row * 40 + col] = make_short4(h0, h1, h2, h3);
            *(short4*)&sSl[row * 40 + col] = make_short4(l0, l1, l2, l3);
        }
        __syncthreads();

        s16x8 ah[4], al[4];
#pragma unroll
        for (int mt = 0; mt < 4; ++mt) {
            int m = wm + mt * 16 + l15;
            ah[mt] = *(const s16x8*)&sSh[m * 40 + quad * 8];
            al[mt] = *(const s16x8*)&sSl[m * 40 + quad * 8];
        }
#pragma unroll
        for (int nt = 0; nt < 4; ++nt) {
            int d = wn + nt * 16 + l15;
            s16x8 bh = *(const s16x8*)&sXh[d * 40 + quad * 8];
            s16x8 bl = *(const s16x8*)&sXl[d * 40 + quad * 8];
#pragma unroll
            for (int mt = 0; mt < 4; ++mt) {
                acc[mt][nt] = __builtin_amdgcn_mfma_f32_16x16x32_bf16(ah[mt], bh, acc[mt][nt], 0, 0, 0);
                acc[mt][nt] = __builtin_amdgcn_mfma_f32_16x16x32_bf16(ah[mt], bl, acc[mt][nt], 0, 0, 0);
                acc[mt][nt] = __builtin_amdgcn_mfma_f32_16x16x32_bf16(al[mt], bh, acc[mt][nt], 0, 0, 0);
            }
        }
    }
#pragma unroll
    for (int mt = 0; mt < 4; ++mt) {
#pragma unroll
        for (int reg = 0; reg < 4; ++reg) {
            int m = wm + mt * 16 + quad * 4 + reg;
#pragma unroll
            for (int nt = 0; nt < 4; ++nt) {
                int d = wn + nt * 16 + l15;
                atomicAdd(&refpt[((size_t)g * CO + m) * CO + d], acc[mt][nt][reg]);
            }
        }
    }
}

// ---------------------------------------------------------------------------
// Attention epilogue
// ---------------------------------------------------------------------------
__global__ void build_kv(const float* __restrict__ refpt, float* __restrict__ kv) {
    int idx = blockIdx.x * 256 + threadIdx.x;
    if (idx >= NB * NR * CO * CO) return;
    int d = idx % CO;
    int j = (idx / CO) % (NR * CO);
    int b = idx / (CO * NR * CO);
    int r = j / CO, cc = j % CO;
    kv[idx] = refpt[(((size_t)r * NB + b) * CO + cc) * CO + d];
}

__global__ void gemm_aw(const float* __restrict__ A, const float* __restrict__ Wm,
                        float* __restrict__ Cm, int M)
{
    int idx = blockIdx.x * 256 + threadIdx.x;
    if (idx >= NB * M * CO) return;
    int c = idx % CO;
    int m = (idx / CO) % M;
    int b = idx / (CO * M);
    const float* ar = A + ((size_t)b * M + m) * CO;
    float acc = 0.f;
    for (int e = 0; e < CO; ++e) acc = fmaf(ar[e], Wm[e * CO + c], acc);
    Cm[idx] = acc;
}

__global__ __launch_bounds__(256) void attn_kernel(const float* __restrict__ qb,
    const float* __restrict__ kb, const float* __restrict__ vb, float* __restrict__ ctx)
{
    __shared__ float sq[CO];
    __shared__ float sl[NR * CO];
    __shared__ float red[4], red2[4];
    const int b = blockIdx.y, i = blockIdx.x;
    const int tid = threadIdx.x;
    if (tid < CO) sq[tid] = qb[((size_t)b * NK + i) * CO + tid];
    __syncthreads();
    const float scale = 0.08838834764831843f;  // 1/sqrt(128)
    for (int j = tid; j < NR * CO; j += 256) {
        const float* kr = kb + ((size_t)b * NR * CO + j) * CO;
        float d = 0.f;
        for (int e = 0; e < CO; ++e) d = fmaf(sq[e], kr[e], d);
        sl[j] = d * scale;
    }
    __syncthreads();
    float m = -1e30f;
    for (int j = tid; j < NR * CO; j += 256) m = fmaxf(m, sl[j]);
#pragma unroll
    for (int off = 32; off; off >>= 1) m = fmaxf(m, __shfl_down(m, off));
    if ((tid & 63) == 0) red[tid >> 6] = m;
    __syncthreads();
    m = fmaxf(fmaxf(red[0], red[1]), fmaxf(red[2], red[3]));
    float s = 0.f;
    for (int j = tid; j < NR * CO; j += 256) { float e = expf(sl[j] - m); sl[j] = e; s += e; }
#pragma unroll
    for (int off = 32; off; off >>= 1) s += __shfl_down(s, off);
    if ((tid & 63) == 0) red2[tid >> 6] = s;
    __syncthreads();
    const float inv = 1.f / (red2[0] + red2[1] + red2[2] + red2[3]);
    if (tid < CO) {
        float acc = 0.f;
        for (int j = 0; j < NR * CO; ++j)
            acc = fmaf(sl[j], vb[((size_t)b * NR * CO + j) * CO + tid], acc);
        ctx[((size_t)b * NK + i) * CO + tid] = acc * inv;
    }
}

__global__ void final_agg(const float* __restrict__ ctx, const float* __restrict__ Wo,
                          const float* __restrict__ tpt, float* __restrict__ out1)
{
    int idx = blockIdx.x * 256 + threadIdx.x;
    if (idx >= NB * NK * CO) return;
    int c = idx % CO;
    const float* cr = ctx + (size_t)(idx / CO) * CO;
    float acc = tpt[idx];
    for (int e = 0; e < CO; ++e) acc = fmaf(cr[e], Wo[e * CO + c], acc);
    out1[idx] = acc;
}

// ---------------------------------------------------------------------------
extern "C" void kernel_launch(void* const* d_in, const int* in_sizes, int n_in,
                              void* d_out, int out_size, void* d_ws, size_t ws_size,
                              hipStream_t stream) {
    (void)in_sizes; (void)n_in; (void)out_size; (void)ws_size;
    const float* target = (const float*)d_in[0];
    const float* ref    = (const float*)d_in[1];
    const float* sqz_w  = (const float*)d_in[2];
    const float* sqz_b  = (const float*)d_in[3];
    const float* slot_w = (const float*)d_in[4];
    const float* slot_b = (const float*)d_in[5];
    const float* Wq     = (const float*)d_in[6];
    const float* Wk     = (const float*)d_in[7];
    const float* Wv     = (const float*)d_in[8];
    const float* Wo     = (const float*)d_in[9];

    float* out  = (float*)d_out;
    float* out0 = out;              // sqz_target (8,128,64,64)  == xt
    float* out1 = out + 4194304;    // agg_pt     (8,64,128)
    float* out2 = out + 4259840;    // ref_pt     (3,8,128,128)
    float* out3 = out + 4653056;    // slot_pt    (8,16,128)
    float* out4 = out + 4669440;    // slot_mask  (8,16,64,64)  == slot probs

    float* ws    = (float*)d_ws;
    float* ssb   = ws;                  //    524,288  slot conv raw
    float* xr    = ssb + 524288;        // 12,582,912  sqz_ref fp32
    float* rmax  = xr + 12582912;       //      3,072
    float* rinv  = rmax + 3072;         //      3,072
    float* cent  = rinv + 3072;         //     65,536
    float* psums = cent + 65536;        //  2,097,152  per-block cluster partials
    float* pcnt  = psums + 2097152;     //     16,384
    float* tpt   = pcnt + 16384;        //     65,536  target_pt fp32
    float* kvb   = tpt + 65536;         //    393,216
    float* qb    = kvb + 393216;        //     65,536
    float* kb    = qb + 65536;          //    393,216
    float* vb    = kb + 393216;         //    393,216
    float* ctxb  = vb + 393216;         //     65,536

    hipMemsetAsync(out3, 0, (size_t)16384 * 4, stream);   // slot_pt accumulator
    hipMemsetAsync(out2, 0, (size_t)393216 * 4, stream);  // ref_pt accumulator

    // convs: target = exact fp32 (kmeans-sensitive, bit-identical retiling),
    // ref = MFMA bf16x3
    conv1x1<64, 128, 32, 4, 8><<<dim3(NHW / 128, CO / 64, NB), 256, 0, stream>>>(
        target, sqz_w, sqz_b, out0);
    conv1x1<16, 256, 32, 4, 4><<<dim3(NHW / 256, 1, NB), 256, 0, stream>>>(
        target, slot_w, slot_b, ssb);
    conv_mfma<<<dim3(NHW / 128, NR * NB), 256, 0, stream>>>(ref, sqz_w, sqz_b, xr);

    // kmeans (xt == out0)
    km_init<<<(NB * NK * CO + 255) / 256, 256, 0, stream>>>(out0, cent);
    for (int it = 0; it < KMITERS; ++it) {
        km_label<<<dim3(32, NB), 1024, 0, stream>>>(out0, cent, psums, pcnt);
        km_update2<<<dim3(NK, NB), 128, 0, stream>>>(cent, tpt, psums, pcnt, 0);
    }
    km_label<<<dim3(32, NB), 1024, 0, stream>>>(out0, cent, psums, pcnt);
    km_update2<<<dim3(NK, NB), 128, 0, stream>>>(cent, tpt, psums, pcnt, 1);

    // slot branch (probs land in out4, slot_pt accumulates in out3)
    slot_softmax<<<(NB * NHW + 255) / 256, 256, 0, stream>>>(ssb, out4);
    slot_pt_kernel<<<dim3(NHW / 256, NB), 256, 0, stream>>>(out4, out0, out3);

    // ref branch (ref_pt accumulates in zeroed out2 via atomics)
    rowstats<<<NR * NB * CO, 256, 0, stream>>>(xr, rmax, rinv);
    refpt_mfma<<<dim3(NHW / 256, NR * NB), 256, 0, stream>>>(xr, rmax, rinv, out2);

    // attention
    build_kv<<<(NB * NR * CO * CO + 255) / 256, 256, 0, stream>>>(out2, kvb);
    gemm_aw<<<(NB * NK * CO + 255) / 256, 256, 0, stream>>>(tpt, Wq, qb, NK);
    gemm_aw<<<(NB * NR * CO * CO + 255) / 256, 256, 0, stream>>>(kvb, Wk, kb, NR * CO);
    gemm_aw<<<(NB * NR * CO * CO + 255) / 256, 256, 0, stream>>>(kvb, Wv, vb, NR * CO);
    attn_kernel<<<dim3(NK, NB), 256, 0, stream>>>(qb, kb, vb, ctxb);
    final_agg<<<(NB * NK * CO + 255) / 256, 256, 0, stream>>>(ctxb, Wo, tpt, out1);
}

// Round 4
// 1125.531 us; speedup vs baseline: 1.1757x; 1.1757x over previous
//
#include <hip/hip_runtime.h>

#define NB 8
#define CIN 512
#define CO 128
#define NS 16
#define NHW 4096
#define NR 3
#define NK 64
#define KMITERS 10

typedef __attribute__((ext_vector_type(8))) short s16x8;
typedef __attribute__((ext_vector_type(4))) float f32x4;

// Truncating hi/lo bf16 split: x ~= hi + lo with |err| <= 2^-16 |x|.
static __device__ __forceinline__ void bsplit(float x, short& h, short& l) {
    union { float f; unsigned u; } a; a.f = x;
    h = (short)(a.u >> 16);
    union { unsigned u; float f; } hf; hf.u = a.u & 0xFFFF0000u;
    union { float f; unsigned u; } r; r.f = x - hf.f;
    l = (short)(r.u >> 16);
}

// One-time W -> bf16 hi/lo split (ref conv weights, reused by 768 blocks).
__global__ void split_w(const float* __restrict__ Wt,
    unsigned short* __restrict__ Whi, unsigned short* __restrict__ Wlo)
{
    int idx = blockIdx.x * 256 + threadIdx.x;
    if (idx >= CO * CIN) return;
    short h, l; bsplit(Wt[idx], h, l);
    Whi[idx] = (unsigned short)h;
    Wlo[idx] = (unsigned short)l;
}

// ---------------------------------------------------------------------------
// MFMA bf16x3 1x1-conv GEMM (ref branch ONLY — smooth consumers, loose tol):
// out[g,m,n] = sum_c W[m,c]*X[g,c,n] + bias[m]
// W pre-split (int4-staged); X packed as (hi<<16|lo) u32 in LDS (bsplit once).
// ---------------------------------------------------------------------------
__global__ __launch_bounds__(256) void conv_mfma(const float* __restrict__ X,
    const unsigned short* __restrict__ Whi, const unsigned short* __restrict__ Wlo,
    const float* __restrict__ bias, float* __restrict__ out)
{
    __shared__ short sWh[128 * 40];     // [m][k] pad 40 (16B-aligned frag reads)
    __shared__ short sWl[128 * 40];
    __shared__ unsigned sXp[32 * 133];  // [k][n] packed bf16 pair, pad 133
    const int g = blockIdx.y;
    const int n0 = blockIdx.x * 128;
    const int tid = threadIdx.x;
    const int lane = tid & 63, w = tid >> 6;
    const int l15 = lane & 15, quad = lane >> 4;
    const int wm = (w & 1) * 64, wn = (w >> 1) * 64;

    f32x4 acc[4][4];
#pragma unroll
    for (int i = 0; i < 4; ++i)
#pragma unroll
        for (int j = 0; j < 4; ++j) acc[i][j] = (f32x4){0.f, 0.f, 0.f, 0.f};

    for (int c0 = 0; c0 < CIN; c0 += 32) {
        if (c0) __syncthreads();
#pragma unroll
        for (int r = 0; r < 2; ++r) {
            int e = (r * 256 + tid) * 8;     // 8-short granules over 128m x 32k
            int m = e >> 5, cc = e & 31;
            *(int4*)&sWh[m * 40 + cc] = *(const int4*)&Whi[(size_t)m * CIN + c0 + cc];
            *(int4*)&sWl[m * 40 + cc] = *(const int4*)&Wlo[(size_t)m * CIN + c0 + cc];
        }
#pragma unroll
        for (int r = 0; r < 4; ++r) {
            int e = r * 1024 + tid * 4;
            int k = e >> 7, n = e & 127;
            const float4 xv = *(const float4*)&X[((size_t)g * CIN + c0 + k) * NHW + n0 + n];
            short h0, l0, h1, l1, h2, l2, h3, l3;
            bsplit(xv.x, h0, l0); bsplit(xv.y, h1, l1);
            bsplit(xv.z, h2, l2); bsplit(xv.w, h3, l3);
            unsigned* p = &sXp[k * 133 + n];
            p[0] = ((unsigned)(unsigned short)h0 << 16) | (unsigned short)l0;
            p[1] = ((unsigned)(unsigned short)h1 << 16) | (unsigned short)l1;
            p[2] = ((unsigned)(unsigned short)h2 << 16) | (unsigned short)l2;
            p[3] = ((unsigned)(unsigned short)h3 << 16) | (unsigned short)l3;
        }
        __syncthreads();

        s16x8 ah[4], al[4];
#pragma unroll
        for (int mt = 0; mt < 4; ++mt) {
            int m = wm + mt * 16 + l15;
            ah[mt] = *(const s16x8*)&sWh[m * 40 + quad * 8];
            al[mt] = *(const s16x8*)&sWl[m * 40 + quad * 8];
        }
#pragma unroll
        for (int nt = 0; nt < 4; ++nt) {
            int n = wn + nt * 16 + l15;
            s16x8 bh, bl;
#pragma unroll
            for (int jj = 0; jj < 8; ++jj) {
                unsigned v = sXp[(quad * 8 + jj) * 133 + n];
                bh[jj] = (short)(v >> 16);
                bl[jj] = (short)(v & 0xffffu);
            }
#pragma unroll
            for (int mt = 0; mt < 4; ++mt) {
                acc[mt][nt] = __builtin_amdgcn_mfma_f32_16x16x32_bf16(ah[mt], bh, acc[mt][nt], 0, 0, 0);
                acc[mt][nt] = __builtin_amdgcn_mfma_f32_16x16x32_bf16(ah[mt], bl, acc[mt][nt], 0, 0, 0);
                acc[mt][nt] = __builtin_amdgcn_mfma_f32_16x16x32_bf16(al[mt], bh, acc[mt][nt], 0, 0, 0);
            }
        }
    }
    // C/D layout: col = lane&15, row = quad*4 + reg
#pragma unroll
    for (int mt = 0; mt < 4; ++mt) {
#pragma unroll
        for (int reg = 0; reg < 4; ++reg) {
            int m = wm + mt * 16 + quad * 4 + reg;
            float bv = bias[m];
#pragma unroll
            for (int nt = 0; nt < 4; ++nt) {
                int n = wn + nt * 16 + l15;
                out[((size_t)g * CO + m) * NHW + n0 + n] = acc[mt][nt][reg] + bv;
            }
        }
    }
}

// ---------------------------------------------------------------------------
// Exact fp32 VALU conv — target branch. KMEANS-EXACTNESS INVARIANT: each
// output element is ONE sequential fmaf chain over c = 0..CIN-1 ascending.
// ---------------------------------------------------------------------------
template<int BM, int BN, int BK, int TM, int TN>
__global__ __launch_bounds__(256) void conv1x1(const float* __restrict__ X,
    const float* __restrict__ Wt, const float* __restrict__ bias,
    float* __restrict__ outf)
{
    static_assert(TM == 4 && (TN == 4 || TN == 8), "mapping assumes TM=4");
    __shared__ float sW[BK][BM + 4];   // +4 keeps 16B row alignment
    __shared__ float sX2[BK][BN + 4];
    const int g  = blockIdx.z;
    const int m0 = blockIdx.y * BM;
    const int n0 = blockIdx.x * BN;
    const int tid = threadIdx.x;
    constexpr int NTH_N = BN / TN;
    const int tn = tid % NTH_N;
    const int tm = tid / NTH_N;
    const int O = gridDim.y * BM;
    const int cb0 = tn * 4;
    const int cb1 = BN / 2 + tn * 4;   // TN==8 only

    float acc[TM][TN];
#pragma unroll
    for (int i = 0; i < TM; ++i)
#pragma unroll
        for (int j = 0; j < TN; ++j) acc[i][j] = 0.f;

    for (int c0 = 0; c0 < CIN; c0 += BK) {
        if (c0) __syncthreads();
        constexpr int F4R = BK / 4;
        for (int idx4 = tid; idx4 < BM * F4R; idx4 += 256) {
            int m = idx4 / F4R, cw = (idx4 % F4R) * 4;
            const float4 wv = *(const float4*)&Wt[(size_t)(m0 + m) * CIN + c0 + cw];
            sW[cw][m] = wv.x; sW[cw + 1][m] = wv.y;
            sW[cw + 2][m] = wv.z; sW[cw + 3][m] = wv.w;
        }
        constexpr int F4N = BN / 4;
        for (int idx4 = tid; idx4 < BK * F4N; idx4 += 256) {
            int k = idx4 / F4N, n4 = (idx4 % F4N) * 4;
            *(float4*)&sX2[k][n4] =
                *(const float4*)&X[((size_t)g * CIN + c0 + k) * NHW + n0 + n4];
        }
        __syncthreads();
#pragma unroll
        for (int k = 0; k < BK; ++k) {
            float a[TM], bb[TN];
            *(float4*)&a[0] = *(const float4*)&sW[k][tm * 4];
            *(float4*)&bb[0] = *(const float4*)&sX2[k][cb0];
            if constexpr (TN == 8)
                *(float4*)&bb[4] = *(const float4*)&sX2[k][cb1];
#pragma unroll
            for (int i = 0; i < TM; ++i)
#pragma unroll
                for (int j = 0; j < TN; ++j) acc[i][j] = fmaf(a[i], bb[j], acc[i][j]);
        }
    }
#pragma unroll
    for (int i = 0; i < TM; ++i) {
        int m = m0 + tm * 4 + i;
        float bv = bias[m];
        float4 o0;
        o0.x = acc[i][0] + bv; o0.y = acc[i][1] + bv;
        o0.z = acc[i][2] + bv; o0.w = acc[i][3] + bv;
        *(float4*)&outf[((size_t)g * O + m) * NHW + n0 + cb0] = o0;
        if constexpr (TN == 8) {
            float4 o1;
            o1.x = acc[i][4] + bv; o1.y = acc[i][5] + bv;
            o1.z = acc[i][6] + bv; o1.w = acc[i][7] + bv;
            *(float4*)&outf[((size_t)g * O + m) * NHW + n0 + cb1] = o1;
        }
    }
}

// ---------------------------------------------------------------------------
// KMeans
// ---------------------------------------------------------------------------
__global__ void km_init(const float* __restrict__ xt, float* __restrict__ cent) {
    int idx = blockIdx.x * 256 + threadIdx.x;
    if (idx >= NB * NK * CO) return;
    int c = idx % CO;
    int k = (idx / CO) % NK;
    int b = idx / (CO * NK);
    cent[idx] = xt[((size_t)b * CO + c) * NHW + 65 * k];
}

// Swizzled centroid LDS index: row k at k*136 + (k>>3)*16B skew, so the
// stride-8-row f32x4 reads of the distance loop hit all 32 banks.
#define CIDX(k, c) ((k) * 136 + (((k) >> 3) << 2) + (c))

// grid (32, NB), 512 thr, 128 points/block, 4pt x 4cl per thread.
// LABELS BIT-IDENTICAL to the proven config: all fmaf chains (p2, dot, c2)
// ascend channels in the same order; argmin is lexicographic min on
// (dist, label) — associative/commutative, so the thread partition and
// 16-lane shuffle tree give the same winner as the 8-lane version.
// f32x4 LDS reads are load-width-only changes (same values, same math).
__global__ __launch_bounds__(512) void km_label(const float* __restrict__ xt,
    const float* __restrict__ cent, float* __restrict__ psums, float* __restrict__ pcnt)
{
    __shared__ float sCent[8736];      // phase1: centroids; phase2: cluster sums
    __shared__ float sXs[32 * 132];    // [c][n] 32-channel chunk
    __shared__ float sC2[64];
    __shared__ float sCnt[64];
    __shared__ int sLab[128];
    const int b = blockIdx.y, nb = blockIdx.x;
    const int n0 = nb * 128;
    const int tid = threadIdx.x;

#pragma unroll
    for (int r = 0; r < 4; ++r) {
        int e = r * 2048 + tid * 4;
        int k = e >> 7, c = e & 127;
        *(f32x4*)&sCent[CIDX(k, c)] = *(const f32x4*)&cent[((size_t)b * NK + k) * CO + c];
    }
    __syncthreads();
    if (tid < 64) {
        float s = 0.f;
        for (int c = 0; c < CO; ++c) { float v = sCent[CIDX(tid, c)]; s = fmaf(v, v, s); }
        sC2[tid] = s;
    }

    const int tn = tid & 15, tm = tid >> 4;   // 4 pts x 4 clusters per thread
    float dot[4][4];
    float p2[4];
#pragma unroll
    for (int i = 0; i < 4; ++i) {
        p2[i] = 0.f;
#pragma unroll
        for (int j = 0; j < 4; ++j) dot[i][j] = 0.f;
    }
    for (int cc = 0; cc < 4; ++cc) {
        __syncthreads();
#pragma unroll
        for (int r = 0; r < 2; ++r) {
            int e = r * 2048 + tid * 4;
            int c = e >> 7, n = e & 127;
            *(f32x4*)&sXs[c * 132 + n] =
                *(const f32x4*)&xt[((size_t)b * CO + cc * 32 + c) * NHW + n0 + n];
        }
        __syncthreads();
        for (int c4 = 0; c4 < 8; ++c4) {
            f32x4 xf[4];
#pragma unroll
            for (int j = 0; j < 4; ++j)
                xf[j] = *(const f32x4*)&sXs[(c4 * 4 + j) * 132 + tm * 4];
#pragma unroll
            for (int j = 0; j < 4; ++j)
#pragma unroll
                for (int i = 0; i < 4; ++i)
                    p2[i] = fmaf(xf[j][i], xf[j][i], p2[i]);
#pragma unroll
            for (int jj = 0; jj < 4; ++jj) {
                int k = tn * 4 + jj;
                f32x4 cf = *(const f32x4*)&sCent[CIDX(k, cc * 32 + c4 * 4)];
#pragma unroll
                for (int j = 0; j < 4; ++j)
#pragma unroll
                    for (int i = 0; i < 4; ++i)
                        dot[i][jj] = fmaf(xf[j][i], cf[j], dot[i][jj]);
            }
        }
    }
    // argmin, first-min tie semantics (within thread ascending k, then lanes)
#pragma unroll
    for (int i = 0; i < 4; ++i) {
        int lab = tn * 4;
        float bd = p2[i] + sC2[tn * 4] - 2.f * dot[i][0];
#pragma unroll
        for (int jj = 1; jj < 4; ++jj) {
            int k = tn * 4 + jj;
            float d = p2[i] + sC2[k] - 2.f * dot[i][jj];
            if (d < bd) { bd = d; lab = k; }
        }
#pragma unroll
        for (int off = 1; off < 16; off <<= 1) {
            float d2 = __shfl_xor(bd, off);
            int l2 = __shfl_xor(lab, off);
            if (d2 < bd || (d2 == bd && l2 < lab)) { bd = d2; lab = l2; }
        }
        if (tn == 0) sLab[tm * 4 + i] = lab;
    }
    __syncthreads();
    for (int e = tid; e < 8736; e += 512) sCent[e] = 0.f;
    if (tid < 64) sCnt[tid] = 0.f;
    __syncthreads();
    if (tid < 128) atomicAdd(&sCnt[sLab[tid]], 1.f);
    for (int cc = 0; cc < 4; ++cc) {
        __syncthreads();
#pragma unroll
        for (int r = 0; r < 2; ++r) {
            int e = r * 2048 + tid * 4;
            int c = e >> 7, n = e & 127;
            *(f32x4*)&sXs[c * 132 + n] =
                *(const f32x4*)&xt[((size_t)b * CO + cc * 32 + c) * NHW + n0 + n];
        }
        __syncthreads();
        if (tid < 256) {
            const int cq = tid & 31, sh = tid >> 5;
            int c = cc * 32 + cq;
            for (int ii = 0; ii < 16; ++ii) {
                int p = sh * 16 + ii;
                atomicAdd(&sCent[CIDX(sLab[p], c)], sXs[cq * 132 + p]);
            }
        }
    }
    __syncthreads();
    float* ps = &psums[((size_t)b * 32 + nb) * (NK * CO)];
    for (int e = tid; e < NK * CO; e += 512) {
        int k = e >> 7, c = e & 127;
        ps[e] = sCent[CIDX(k, c)];
    }
    if (tid < 64) pcnt[((size_t)b * 32 + nb) * 64 + tid] = sCnt[tid];
}

// grid (NK, NB), 128 thr: reduce 32 partials; mode 0 -> centroid update, 1 -> tpt
__global__ void km_update2(float* __restrict__ cent, float* __restrict__ tpt,
    const float* __restrict__ psums, const float* __restrict__ pcnt, int mode)
{
    const int k = blockIdx.x, b = blockIdx.y, c = threadIdx.x;
    float s = 0.f;
    for (int nb = 0; nb < 32; ++nb)
        s += psums[((size_t)b * 32 + nb) * (NK * CO) + k * CO + c];
    if (mode) { tpt[((size_t)b * NK + k) * CO + c] = s; return; }
    float cn = 0.f;
    for (int nb = 0; nb < 32; ++nb)
        cn += pcnt[((size_t)b * 32 + nb) * 64 + k];
    if (cn > 0.f) cent[((size_t)b * NK + k) * CO + c] = s / fmaxf(cn, 1.f);
}

// ---------------------------------------------------------------------------
// Slot branch
// ---------------------------------------------------------------------------
__global__ void slot_softmax(const float* __restrict__ ssb, float* __restrict__ out4) {
    int idx = blockIdx.x * 256 + threadIdx.x;
    if (idx >= NB * NHW) return;
    int b = idx / NHW, n = idx % NHW;
    float v[NS];
    float m = -1e30f;
#pragma unroll
    for (int s = 0; s < NS; ++s) { v[s] = ssb[((size_t)b * NS + s) * NHW + n]; m = fmaxf(m, v[s]); }
    float sum = 0.f;
#pragma unroll
    for (int s = 0; s < NS; ++s) { v[s] = expf(v[s] - m); sum += v[s]; }
    float inv = 1.f / sum;
#pragma unroll
    for (int s = 0; s < NS; ++s)
        out4[((size_t)b * NS + s) * NHW + n] = v[s] * inv;
}

__global__ __launch_bounds__(256) void slot_pt_kernel(const float* __restrict__ ss,
    const float* __restrict__ xt, float* __restrict__ spt)
{
    __shared__ float sS[NS][257];
    __shared__ float sX2[32][257];
    const int b = blockIdx.y;
    const int n0 = blockIdx.x * 256;
    const int tid = threadIdx.x;
    for (int i = tid; i < NS * 256; i += 256) {
        int s = i >> 8, nn = i & 255;
        sS[s][nn] = ss[((size_t)b * NS + s) * NHW + n0 + nn];
    }
    const int c = tid & 31;
    const int sA = tid >> 5;
    for (int cg = 0; cg < 4; ++cg) {
        __syncthreads();
        for (int i = tid; i < 32 * 256; i += 256) {
            int cc = i >> 8, nn = i & 255;
            sX2[cc][nn] = xt[((size_t)b * CO + cg * 32 + cc) * NHW + n0 + nn];
        }
        __syncthreads();
        float a0 = 0.f, a1 = 0.f;
        for (int nn = 0; nn < 256; ++nn) {
            float x = sX2[c][nn];
            a0 = fmaf(x, sS[sA][nn], a0);
            a1 = fmaf(x, sS[sA + 8][nn], a1);
        }
        atomicAdd(&spt[((size_t)b * NS + sA) * CO + cg * 32 + c], a0);
        atomicAdd(&spt[((size_t)b * NS + sA + 8) * CO + cg * 32 + c], a1);
    }
}

// ---------------------------------------------------------------------------
// Ref branch
// ---------------------------------------------------------------------------
__global__ __launch_bounds__(256) void rowstats(const float* __restrict__ xr,
    float* __restrict__ rmax, float* __restrict__ rinv)
{
    const int row = blockIdx.x;
    const float* p = xr + (size_t)row * NHW;
    const int tid = threadIdx.x;
    float v[16];
    float m = -1e30f;
#pragma unroll
    for (int i = 0; i < 16; ++i) { v[i] = p[tid + (i << 8)]; m = fmaxf(m, v[i]); }
#pragma unroll
    for (int off = 32; off; off >>= 1) m = fmaxf(m, __shfl_down(m, off));
    __shared__ float sm[4];
    __shared__ float ss2[4];
    const int wid = tid >> 6, lane = tid & 63;
    if (lane == 0) sm[wid] = m;
    __syncthreads();
    m = fmaxf(fmaxf(sm[0], sm[1]), fmaxf(sm[2], sm[3]));
    float s = 0.f;
#pragma unroll
    for (int i = 0; i < 16; ++i) s += expf(v[i] - m);
#pragma unroll
    for (int off = 32; off; off >>= 1) s += __shfl_down(s, off);
    if (lane == 0) ss2[wid] = s;
    __syncthreads();
    if (tid == 0) {
        rmax[row] = m;
        rinv[row] = 1.f / (ss2[0] + ss2[1] + ss2[2] + ss2[3]);
    }
}

// ref_pt[g,c,d] = sum_n softmax(xr[g,c,:])[n] * xr[g,d,n]
// MFMA bf16x3, spatial-split, fp32 atomicAdd into zeroed out2.
__global__ __launch_bounds__(256) void refpt_mfma(const float* __restrict__ xr,
    const float* __restrict__ rmax, const float* __restrict__ rinv,
    float* __restrict__ refpt)
{
    __shared__ short sSh[128 * 40];  // softmax(S) hi   [c][k] pad 40
    __shared__ short sSl[128 * 40];  // softmax(S) lo
    __shared__ short sXh[128 * 40];  // raw X hi        [d][k] pad 40
    __shared__ short sXl[128 * 40];  // raw X lo
    __shared__ float sMax[CO];
    __shared__ float sInv[CO];
    const int g = blockIdx.y;
    const int n0 = blockIdx.x * 256;   // this block's 256-wide spatial chunk
    const int tid = threadIdx.x;
    const int lane = tid & 63, w = tid >> 6;
    const int l15 = lane & 15, quad = lane >> 4;
    const int wm = (w & 1) * 64, wn = (w >> 1) * 64;
    const float* base = xr + (size_t)g * CO * NHW;

    if (tid < CO) {
        sMax[tid] = rmax[g * CO + tid];
        sInv[tid] = rinv[g * CO + tid];
    }

    f32x4 acc[4][4];
#pragma unroll
    for (int i = 0; i < 4; ++i)
#pragma unroll
        for (int j = 0; j < 4; ++j) acc[i][j] = (f32x4){0.f, 0.f, 0.f, 0.f};

    for (int ks = 0; ks < 8; ++ks) {   // 8 sub-chunks of 32 spatial cols
        __syncthreads();               // covers sMax init and prev-iter reads
#pragma unroll
        for (int r = 0; r < 4; ++r) {
            int e = r * 1024 + tid * 4;
            int row = e >> 5, col = e & 31;
            const float4 xv = *(const float4*)&base[(size_t)row * NHW + n0 + ks * 32 + col];
            const float mx = sMax[row], iv = sInv[row];
            short h0, l0, h1, l1, h2, l2, h3, l3;
            bsplit(xv.x, h0, l0); bsplit(xv.y, h1, l1);
            bsplit(xv.z, h2, l2); bsplit(xv.w, h3, l3);
            *(short4*)&sXh[row * 40 + col] = make_short4(h0, h1, h2, h3);
            *(short4*)&sXl[row * 40 + col] = make_short4(l0, l1, l2, l3);
            float s0 = expf(xv.x - mx) * iv, s1 = expf(xv.y - mx) * iv;
            float s2 = expf(xv.z - mx) * iv, s3 = expf(xv.w - mx) * iv;
            bsplit(s0, h0, l0); bsplit(s1, h1, l1);
            bsplit(s2, h2, l2); bsplit(s3, h3, l3);
            *(short4*)&sSh[row * 40 + col] = make_short4(h0, h1, h2, h3);
            *(short4*)&sSl[row * 40 + col] = make_short4(l0, l1, l2, l3);
        }
        __syncthreads();

        s16x8 ah[4], al[4];
#pragma unroll
        for (int mt = 0; mt < 4; ++mt) {
            int m = wm + mt * 16 + l15;
            ah[mt] = *(const s16x8*)&sSh[m * 40 + quad * 8];
            al[mt] = *(const s16x8*)&sSl[m * 40 + quad * 8];
        }
#pragma unroll
        for (int nt = 0; nt < 4; ++nt) {
            int d = wn + nt * 16 + l15;
            s16x8 bh = *(const s16x8*)&sXh[d * 40 + quad * 8];
            s16x8 bl = *(const s16x8*)&sXl[d * 40 + quad * 8];
#pragma unroll
            for (int mt = 0; mt < 4; ++mt) {
                acc[mt][nt] = __builtin_amdgcn_mfma_f32_16x16x32_bf16(ah[mt], bh, acc[mt][nt], 0, 0, 0);
                acc[mt][nt] = __builtin_amdgcn_mfma_f32_16x16x32_bf16(ah[mt], bl, acc[mt][nt], 0, 0, 0);
                acc[mt][nt] = __builtin_amdgcn_mfma_f32_16x16x32_bf16(al[mt], bh, acc[mt][nt], 0, 0, 0);
            }
        }
    }
#pragma unroll
    for (int mt = 0; mt < 4; ++mt) {
#pragma unroll
        for (int reg = 0; reg < 4; ++reg) {
            int m = wm + mt * 16 + quad * 4 + reg;
#pragma unroll
            for (int nt = 0; nt < 4; ++nt) {
                int d = wn + nt * 16 + l15;
                atomicAdd(&refpt[((size_t)g * CO + m) * CO + d], acc[mt][nt][reg]);
            }
        }
    }
}

// ---------------------------------------------------------------------------
// Attention epilogue
// ---------------------------------------------------------------------------
__global__ void build_kv(const float* __restrict__ refpt, float* __restrict__ kv) {
    int idx = blockIdx.x * 256 + threadIdx.x;
    if (idx >= NB * NR * CO * CO) return;
    int d = idx % CO;
    int j = (idx / CO) % (NR * CO);
    int b = idx / (CO * NR * CO);
    int r = j / CO, cc = j % CO;
    kv[idx] = refpt[(((size_t)r * NB + b) * CO + cc) * CO + d];
}

__global__ void gemm_aw(const float* __restrict__ A, const float* __restrict__ Wm,
                        float* __restrict__ Cm, int M)
{
    int idx = blockIdx.x * 256 + threadIdx.x;
    if (idx >= NB * M * CO) return;
    int c = idx % CO;
    int m = (idx / CO) % M;
    int b = idx / (CO * M);
    const float* ar = A + ((size_t)b * M + m) * CO;
    float acc = 0.f;
    for (int e = 0; e < CO; ++e) acc = fmaf(ar[e], Wm[e * CO + c], acc);
    Cm[idx] = acc;
}

__global__ __launch_bounds__(256) void attn_kernel(const float* __restrict__ qb,
    const float* __restrict__ kb, const float* __restrict__ vb, float* __restrict__ ctx)
{
    __shared__ float sq[CO];
    __shared__ float sl[NR * CO];
    __shared__ float red[4], red2[4];
    const int b = blockIdx.y, i = blockIdx.x;
    const int tid = threadIdx.x;
    if (tid < CO) sq[tid] = qb[((size_t)b * NK + i) * CO + tid];
    __syncthreads();
    const float scale = 0.08838834764831843f;  // 1/sqrt(128)
    for (int j = tid; j < NR * CO; j += 256) {
        const float* kr = kb + ((size_t)b * NR * CO + j) * CO;
        float d = 0.f;
        for (int e = 0; e < CO; ++e) d = fmaf(sq[e], kr[e], d);
        sl[j] = d * scale;
    }
    __syncthreads();
    float m = -1e30f;
    for (int j = tid; j < NR * CO; j += 256) m = fmaxf(m, sl[j]);
#pragma unroll
    for (int off = 32; off; off >>= 1) m = fmaxf(m, __shfl_down(m, off));
    if ((tid & 63) == 0) red[tid >> 6] = m;
    __syncthreads();
    m = fmaxf(fmaxf(red[0], red[1]), fmaxf(red[2], red[3]));
    float s = 0.f;
    for (int j = tid; j < NR * CO; j += 256) { float e = expf(sl[j] - m); sl[j] = e; s += e; }
#pragma unroll
    for (int off = 32; off; off >>= 1) s += __shfl_down(s, off);
    if ((tid & 63) == 0) red2[tid >> 6] = s;
    __syncthreads();
    const float inv = 1.f / (red2[0] + red2[1] + red2[2] + red2[3]);
    if (tid < CO) {
        float acc = 0.f;
        for (int j = 0; j < NR * CO; ++j)
            acc = fmaf(sl[j], vb[((size_t)b * NR * CO + j) * CO + tid], acc);
        ctx[((size_t)b * NK + i) * CO + tid] = acc * inv;
    }
}

__global__ void final_agg(const float* __restrict__ ctx, const float* __restrict__ Wo,
                          const float* __restrict__ tpt, float* __restrict__ out1)
{
    int idx = blockIdx.x * 256 + threadIdx.x;
    if (idx >= NB * NK * CO) return;
    int c = idx % CO;
    const float* cr = ctx + (size_t)(idx / CO) * CO;
    float acc = tpt[idx];
    for (int e = 0; e < CO; ++e) acc = fmaf(cr[e], Wo[e * CO + c], acc);
    out1[idx] = acc;
}

// ---------------------------------------------------------------------------
extern "C" void kernel_launch(void* const* d_in, const int* in_sizes, int n_in,
                              void* d_out, int out_size, void* d_ws, size_t ws_size,
                              hipStream_t stream) {
    (void)in_sizes; (void)n_in; (void)out_size; (void)ws_size;
    const float* target = (const float*)d_in[0];
    const float* ref    = (const float*)d_in[1];
    const float* sqz_w  = (const float*)d_in[2];
    const float* sqz_b  = (const float*)d_in[3];
    const float* slot_w = (const float*)d_in[4];
    const float* slot_b = (const float*)d_in[5];
    const float* Wq     = (const float*)d_in[6];
    const float* Wk     = (const float*)d_in[7];
    const float* Wv     = (const float*)d_in[8];
    const float* Wo     = (const float*)d_in[9];

    float* out  = (float*)d_out;
    float* out0 = out;              // sqz_target (8,128,64,64)  == xt
    float* out1 = out + 4194304;    // agg_pt     (8,64,128)
    float* out2 = out + 4259840;    // ref_pt     (3,8,128,128)
    float* out3 = out + 4653056;    // slot_pt    (8,16,128)
    float* out4 = out + 4669440;    // slot_mask  (8,16,64,64)  == slot probs

    float* ws    = (float*)d_ws;
    float* ssb   = ws;                  //    524,288  slot conv raw
    float* xr    = ssb + 524288;        // 12,582,912  sqz_ref fp32
    float* rmax  = xr + 12582912;       //      3,072
    float* rinv  = rmax + 3072;         //      3,072
    float* cent  = rinv + 3072;         //     65,536
    float* psums = cent + 65536;        //  2,097,152  per-block cluster partials
    float* pcnt  = psums + 2097152;     //     16,384
    float* tpt   = pcnt + 16384;        //     65,536  target_pt fp32
    float* kvb   = tpt + 65536;         //    393,216
    float* qb    = kvb + 393216;        //     65,536
    float* kb    = qb + 65536;          //    393,216
    float* vb    = kb + 393216;         //    393,216
    float* ctxb  = vb + 393216;         //     65,536
    unsigned short* Whi = (unsigned short*)(ctxb + 65536);  // 65,536 u16
    unsigned short* Wlo = Whi + CO * CIN;                   // 65,536 u16

    hipMemsetAsync(out3, 0, (size_t)16384 * 4, stream);   // slot_pt accumulator
    hipMemsetAsync(out2, 0, (size_t)393216 * 4, stream);  // ref_pt accumulator

    // convs: target = exact fp32 (kmeans-sensitive), ref = MFMA bf16x3
    split_w<<<(CO * CIN + 255) / 256, 256, 0, stream>>>(sqz_w, Whi, Wlo);
    conv1x1<64, 128, 32, 4, 8><<<dim3(NHW / 128, CO / 64, NB), 256, 0, stream>>>(
        target, sqz_w, sqz_b, out0);
    conv1x1<16, 256, 32, 4, 4><<<dim3(NHW / 256, 1, NB), 256, 0, stream>>>(
        target, slot_w, slot_b, ssb);
    conv_mfma<<<dim3(NHW / 128, NR * NB), 256, 0, stream>>>(ref, Whi, Wlo, sqz_b, xr);

    // kmeans (xt == out0)
    km_init<<<(NB * NK * CO + 255) / 256, 256, 0, stream>>>(out0, cent);
    for (int it = 0; it < KMITERS; ++it) {
        km_label<<<dim3(32, NB), 512, 0, stream>>>(out0, cent, psums, pcnt);
        km_update2<<<dim3(NK, NB), 128, 0, stream>>>(cent, tpt, psums, pcnt, 0);
    }
    km_label<<<dim3(32, NB), 512, 0, stream>>>(out0, cent, psums, pcnt);
    km_update2<<<dim3(NK, NB), 128, 0, stream>>>(cent, tpt, psums, pcnt, 1);

    // slot branch (probs land in out4, slot_pt accumulates in out3)
    slot_softmax<<<(NB * NHW + 255) / 256, 256, 0, stream>>>(ssb, out4);
    slot_pt_kernel<<<dim3(NHW / 256, NB), 256, 0, stream>>>(out4, out0, out3);

    // ref branch (ref_pt accumulates in zeroed out2 via atomics)
    rowstats<<<NR * NB * CO, 256, 0, stream>>>(xr, rmax, rinv);
    refpt_mfma<<<dim3(NHW / 256, NR * NB), 256, 0, stream>>>(xr, rmax, rinv, out2);

    // attention
    build_kv<<<(NB * NR * CO * CO + 255) / 256, 256, 0, stream>>>(out2, kvb);
    gemm_aw<<<(NB * NK * CO + 255) / 256, 256, 0, stream>>>(tpt, Wq, qb, NK);
    gemm_aw<<<(NB * NR * CO * CO + 255) / 256, 256, 0, stream>>>(kvb, Wk, kb, NR * CO);
    gemm_aw<<<(NB * NR * CO * CO + 255) / 256, 256, 0, stream>>>(kvb, Wv, vb, NR * CO);
    attn_kernel<<<dim3(NK, NB), 256, 0, stream>>>(qb, kb, vb, ctxb);
    final_agg<<<(NB * NK * CO + 255) / 256, 256, 0, stream>>>(ctxb, Wo, tpt, out1);
}